// Round 1
// baseline (73.794 us; speedup 1.0000x reference)
//
#include <hip/hip_runtime.h>
#include <math.h>

#define BB 8
#define SS 512
#define DD 256
#define PP (SS * (SS - 1) / 2)      // 130816 pairs per batch
#define TILES_PER_B (32 * 33 / 2)   // 528 triangular 16x16 tiles per batch

typedef short bf16x8 __attribute__((ext_vector_type(8)));
typedef float f32x4 __attribute__((ext_vector_type(4)));

// fp32 -> bf16 round-to-nearest-even (inputs are finite gaussians, no NaN path)
static __device__ inline unsigned short f2bf(float f) {
    unsigned int u = __float_as_uint(f);
    unsigned int r = u + 0x7fffu + ((u >> 16) & 1u);
    return (unsigned short)(r >> 16);
}

static __device__ inline bf16x8 cvt8(float4 a0, float4 a1) {
    bf16x8 v;
    v[0] = (short)f2bf(a0.x); v[1] = (short)f2bf(a0.y);
    v[2] = (short)f2bf(a0.z); v[3] = (short)f2bf(a0.w);
    v[4] = (short)f2bf(a1.x); v[5] = (short)f2bf(a1.y);
    v[6] = (short)f2bf(a1.z); v[7] = (short)f2bf(a1.w);
    return v;
}

static __device__ inline float ssq8(float4 a0, float4 a1) {
    return a0.x*a0.x + a0.y*a0.y + a0.z*a0.z + a0.w*a0.w
         + a1.x*a1.x + a1.y*a1.y + a1.z*a1.z + a1.w*a1.w;
}

// Fully fused: one wave per 16x16 lower-triangular tile.
// Each lane loads its own MFMA fragment straight from fp32 x (32B/lane/K-step),
// converts to bf16 in-register, and accumulates fp32 sum-of-squares for the
// norms on the fly (recovered with two shfl_xor reductions).
__global__ __launch_bounds__(256) void dist_fused(const float* __restrict__ x,
                                                  float* __restrict__ out) {
    int w    = blockIdx.x * 4 + (threadIdx.x >> 6); // 0..4223
    int lane = threadIdx.x & 63;
    int b    = w / TILES_PER_B;
    int tidx = w - b * TILES_PER_B;
    // largest ti with ti*(ti+1)/2 <= tidx
    int ti = (int)((sqrtf(8.0f * (float)tidx + 1.0f) - 1.0f) * 0.5f);
    while ((ti + 1) * (ti + 2) / 2 <= tidx) ti++;
    while (ti * (ti + 1) / 2 > tidx) ti--;
    int tj = tidx - ti * (ti + 1) / 2;

    int nidx = lane & 15;  // row within 16-row strip (A and B operand row)
    int quad = lane >> 4;  // k-quad for operands; row-quad for C/D

    const float* arow = x + ((size_t)(b * SS + ti * 16 + nidx)) * DD + quad * 8;
    const float* brow = x + ((size_t)(b * SS + tj * 16 + nidx)) * DD + quad * 8;

    f32x4 acc = {0.f, 0.f, 0.f, 0.f};
    float psA = 0.f, psB = 0.f;
    #pragma unroll
    for (int k = 0; k < DD; k += 32) {
        float4 a0 = *reinterpret_cast<const float4*>(arow + k);
        float4 a1 = *reinterpret_cast<const float4*>(arow + k + 4);
        float4 b0 = *reinterpret_cast<const float4*>(brow + k);
        float4 b1 = *reinterpret_cast<const float4*>(brow + k + 4);
        psA += ssq8(a0, a1);
        psB += ssq8(b0, b1);
        bf16x8 av = cvt8(a0, a1);
        bf16x8 bv = cvt8(b0, b1);
        acc = __builtin_amdgcn_mfma_f32_16x16x32_bf16(av, bv, acc, 0, 0, 0);
    }

    // Each lane holds partial ssq of 64 elems of row (lane&15) / k-chunk quad.
    // Reduce over the 4 quads -> every lane holds the full norm of row lane&15.
    psA += __shfl_xor(psA, 16); psA += __shfl_xor(psA, 32);
    psB += __shfl_xor(psB, 16); psB += __shfl_xor(psB, 32);

    // C/D layout (m89-verified): col = lane&15 -> j index, row = quad*4+reg -> i
    int jg = tj * 16 + nidx;
    float nj = psB;
    float* outb = out + (size_t)b * PP;
    #pragma unroll
    for (int r = 0; r < 4; r++) {
        int il = quad * 4 + r;          // local A-row of this accumulator reg
        int ig = ti * 16 + il;
        float ni = __shfl(psA, il);     // A-norm lives in lane il (il<16)
        if (ig > jg) {
            float d2 = ni + nj - 2.0f * acc[r];
            d2 = fmaxf(d2, 1e-7f);
            outb[(size_t)(ig * (ig - 1) / 2) + jg] = sqrtf(d2);
        }
    }
}

extern "C" void kernel_launch(void* const* d_in, const int* in_sizes, int n_in,
                              void* d_out, int out_size, void* d_ws, size_t ws_size,
                              hipStream_t stream) {
    const float* x = (const float*)d_in[0];
    float* out = (float*)d_out;
    (void)d_ws; (void)ws_size; // workspace no longer needed
    dist_fused<<<1056, 256, 0, stream>>>(x, out);
}

// Round 2
// 69.107 us; speedup vs baseline: 1.0678x; 1.0678x over previous
//
#include <hip/hip_runtime.h>
#include <math.h>

#define BB 8
#define SS 512
#define DD 256
#define PP (SS * (SS - 1) / 2)          // 130816 pairs per batch
#define STRIPS 16                        // 32-row strips per batch
#define SUPER_PER_B (STRIPS * (STRIPS + 1) / 2)  // 136 triangular 32x32 supertiles

typedef short bf16x8 __attribute__((ext_vector_type(8)));
typedef float f32x4 __attribute__((ext_vector_type(4)));

// fp32 -> bf16 round-to-nearest-even (inputs are finite gaussians, no NaN path)
static __device__ inline unsigned short f2bf(float f) {
    unsigned int u = __float_as_uint(f);
    unsigned int r = u + 0x7fffu + ((u >> 16) & 1u);
    return (unsigned short)(r >> 16);
}

// One wave per row: convert 256 fp32 -> bf16 once, fp32 sum of squares.
__global__ __launch_bounds__(256) void prep_kernel(const float* __restrict__ x,
                                                   unsigned short* __restrict__ xb,
                                                   float* __restrict__ norms) {
    int row  = blockIdx.x * 4 + (threadIdx.x >> 6); // 4096 rows total
    int lane = threadIdx.x & 63;
    const float4* src = reinterpret_cast<const float4*>(x + (size_t)row * DD) + lane;
    float4 v = *src;
    float ss = v.x * v.x + v.y * v.y + v.z * v.z + v.w * v.w;
    ushort4 pk;
    pk.x = f2bf(v.x); pk.y = f2bf(v.y); pk.z = f2bf(v.z); pk.w = f2bf(v.w);
    *reinterpret_cast<ushort4*>(xb + (size_t)row * DD + lane * 4) = pk;
    #pragma unroll
    for (int o = 32; o > 0; o >>= 1) ss += __shfl_down(ss, o);
    if (lane == 0) norms[row] = ss;
}

// One wave per 32x32 supertile (2x2 grid of 16x16 MFMA tiles).
// 4 independent accumulator chains (ILP=4) + one-step operand prefetch.
// L2 traffic: 32 B/output (half of the 16x16/wave version).
__global__ __launch_bounds__(256) void dist_kernel(const unsigned short* __restrict__ xb,
                                                   const float* __restrict__ norms,
                                                   float* __restrict__ out) {
    int w    = blockIdx.x * 4 + (threadIdx.x >> 6); // 0..1087
    int lane = threadIdx.x & 63;
    int b    = w / SUPER_PER_B;
    int s    = w - b * SUPER_PER_B;
    // largest ti with ti*(ti+1)/2 <= s
    int ti = (int)((sqrtf(8.0f * (float)s + 1.0f) - 1.0f) * 0.5f);
    while ((ti + 1) * (ti + 2) / 2 <= s) ti++;
    while (ti * (ti + 1) / 2 > s) ti--;
    int tj = s - ti * (ti + 1) / 2;      // tj <= ti, 32-row strip indices

    int r16 = lane & 15;   // operand row within 16-row tile; C/D col (j)
    int kq  = lane >> 4;   // operand k-quad; C/D row-quad (i)

    const unsigned short* base = xb + (size_t)b * SS * DD;
    const unsigned short* a0r = base + (size_t)(ti * 32 + r16) * DD + kq * 8;
    const unsigned short* a1r = a0r + 16 * DD;
    const unsigned short* b0r = base + (size_t)(tj * 32 + r16) * DD + kq * 8;
    const unsigned short* b1r = b0r + 16 * DD;

    f32x4 acc00 = {0.f,0.f,0.f,0.f}, acc01 = {0.f,0.f,0.f,0.f};
    f32x4 acc10 = {0.f,0.f,0.f,0.f}, acc11 = {0.f,0.f,0.f,0.f};

    bf16x8 a0 = *reinterpret_cast<const bf16x8*>(a0r);
    bf16x8 a1 = *reinterpret_cast<const bf16x8*>(a1r);
    bf16x8 b0 = *reinterpret_cast<const bf16x8*>(b0r);
    bf16x8 b1 = *reinterpret_cast<const bf16x8*>(b1r);

    #pragma unroll
    for (int k = 32; k <= DD; k += 32) {
        bf16x8 na0, na1, nb0, nb1;
        if (k < DD) {                     // prefetch next K-step
            na0 = *reinterpret_cast<const bf16x8*>(a0r + k);
            na1 = *reinterpret_cast<const bf16x8*>(a1r + k);
            nb0 = *reinterpret_cast<const bf16x8*>(b0r + k);
            nb1 = *reinterpret_cast<const bf16x8*>(b1r + k);
        }
        acc00 = __builtin_amdgcn_mfma_f32_16x16x32_bf16(a0, b0, acc00, 0, 0, 0);
        acc01 = __builtin_amdgcn_mfma_f32_16x16x32_bf16(a0, b1, acc01, 0, 0, 0);
        acc10 = __builtin_amdgcn_mfma_f32_16x16x32_bf16(a1, b0, acc10, 0, 0, 0);
        acc11 = __builtin_amdgcn_mfma_f32_16x16x32_bf16(a1, b1, acc11, 0, 0, 0);
        if (k < DD) { a0 = na0; a1 = na1; b0 = nb0; b1 = nb1; }
    }

    // C/D layout (m89-verified): col = lane&15 -> j, row = kq*4 + reg -> i
    const float* nrm = norms + b * SS;
    float* outb = out + (size_t)b * PP;
    #pragma unroll
    for (int q = 0; q < 2; q++) {
        int jg = tj * 32 + q * 16 + r16;
        float nj = nrm[jg];
        const f32x4& accq0 = (q == 0) ? acc00 : acc01;   // compile-time after unroll
        const f32x4& accq1 = (q == 0) ? acc10 : acc11;
        #pragma unroll
        for (int p = 0; p < 2; p++) {
            const f32x4& a = (p == 0) ? accq0 : accq1;
            #pragma unroll
            for (int r = 0; r < 4; r++) {
                int ig = ti * 32 + p * 16 + kq * 4 + r;
                if (ig > jg) {
                    float ni = nrm[ig];
                    float d2 = ni + nj - 2.0f * a[r];
                    d2 = fmaxf(d2, 1e-7f);
                    outb[(size_t)(ig * (ig - 1) / 2) + jg] = sqrtf(d2);
                }
            }
        }
    }
}

extern "C" void kernel_launch(void* const* d_in, const int* in_sizes, int n_in,
                              void* d_out, int out_size, void* d_ws, size_t ws_size,
                              hipStream_t stream) {
    const float* x = (const float*)d_in[0];
    float* out = (float*)d_out;
    unsigned short* xb = (unsigned short*)d_ws;                      // 2 MB bf16 copy
    float* norms = (float*)((char*)d_ws + (size_t)BB * SS * DD * 2); // 16 KB norms

    prep_kernel<<<1024, 256, 0, stream>>>(x, xb, norms);
    dist_kernel<<<272, 256, 0, stream>>>(xb, norms, out);
}